// Round 8
// baseline (548.190 us; speedup 1.0000x reference)
//
#include <hip/hip_runtime.h>
#include <hip/hip_bf16.h>

// ---------------------------------------------------------------------------
// RESK2 4-layer GCN on MI355X — round 8.
//  GEMM rework: swapped MFMA operands (compute C^T tile) so each lane holds
//  4 consecutive output cols -> uint2 stores (was 64 scattered 2B stores);
//  register-prefetch software pipeline on the K-loop staging.
//  Everything else as round 7 (packed 4B perm, single-writer CSR sort).
// ---------------------------------------------------------------------------

typedef __attribute__((ext_vector_type(8))) short short8;
typedef __attribute__((ext_vector_type(4))) float float4v;

#define SC_SHIFT 8              // 256 nodes per sub-chunk
#define SC_NODES 256
#define FILL_CAP 12288          // LDS edge capacity in fill2 (mean ~4096)
#define SRC_MASK 0x1FFFF        // 17 bits (N=100000 < 131072)

static __device__ __forceinline__ float bf2f_lo(unsigned int v) {
    return __uint_as_float(v << 16);
}
static __device__ __forceinline__ float bf2f_hi(unsigned int v) {
    return __uint_as_float(v & 0xffff0000u);
}
static __device__ __forceinline__ unsigned short f2bf(float f) {
    unsigned int u = __float_as_uint(f);
    u = (u + 0x7fffu + ((u >> 16) & 1u)) >> 16;  // RNE
    return (unsigned short)u;
}
static __device__ __forceinline__ unsigned int packbf(float a, float b) {
    return (unsigned int)f2bf(a) | ((unsigned int)f2bf(b) << 16);
}
static __device__ __forceinline__ float pw_w(unsigned int pe) {
    return __uint_as_float((pe >> 17) << 16);
}

static __device__ __forceinline__ void acc8(float* acc, uint4 v, float wt) {
    acc[0] = fmaf(bf2f_lo(v.x), wt, acc[0]);
    acc[1] = fmaf(bf2f_hi(v.x), wt, acc[1]);
    acc[2] = fmaf(bf2f_lo(v.y), wt, acc[2]);
    acc[3] = fmaf(bf2f_hi(v.y), wt, acc[3]);
    acc[4] = fmaf(bf2f_lo(v.z), wt, acc[4]);
    acc[5] = fmaf(bf2f_hi(v.z), wt, acc[5]);
    acc[6] = fmaf(bf2f_lo(v.w), wt, acc[6]);
    acc[7] = fmaf(bf2f_hi(v.w), wt, acc[7]);
}
static __device__ __forceinline__ void acc4(float* acc, uint2 v, float wt) {
    acc[0] = fmaf(bf2f_lo(v.x), wt, acc[0]);
    acc[1] = fmaf(bf2f_hi(v.x), wt, acc[1]);
    acc[2] = fmaf(bf2f_lo(v.y), wt, acc[2]);
    acc[3] = fmaf(bf2f_hi(v.y), wt, acc[3]);
}

// --------------------- CSR stage 1: bucket histogram -----------------------
__global__ __launch_bounds__(256) void k_count(const int* __restrict__ tgt,
                                               int* __restrict__ chunkTot,
                                               int E, int NSC) {
    __shared__ int hist[512];
    const int tid = threadIdx.x;
    hist[tid] = 0;
    hist[tid + 256] = 0;
    __syncthreads();
#pragma unroll
    for (int r = 0; r < 4; r++) {
        int e = blockIdx.x * 4096 + r * 1024 + tid * 4;
        if (e + 3 < E) {
            int4 tv = *(const int4*)&tgt[e];
            atomicAdd(&hist[tv.x >> SC_SHIFT], 1);
            atomicAdd(&hist[tv.y >> SC_SHIFT], 1);
            atomicAdd(&hist[tv.z >> SC_SHIFT], 1);
            atomicAdd(&hist[tv.w >> SC_SHIFT], 1);
        } else {
            for (int j = 0; j < 4; j++)
                if (e + j < E) atomicAdd(&hist[tgt[e + j] >> SC_SHIFT], 1);
        }
    }
    __syncthreads();
    for (int i = tid; i < NSC; i += 256) {
        int c = hist[i];
        if (c) atomicAdd(&chunkTot[i], c);
    }
}

// --------------------- CSR stage 2: bucket prefix scan ---------------------
__global__ __launch_bounds__(512) void k_scanB(const int* __restrict__ chunkTot,
                                               int* __restrict__ chunkStart,
                                               int* __restrict__ chunkCur,
                                               int E, int NSC) {
    __shared__ int sm[512];
    const int tid = threadIdx.x;
    int v = (tid < NSC) ? chunkTot[tid] : 0;
    sm[tid] = v;
    __syncthreads();
    for (int off = 1; off < 512; off <<= 1) {
        int t = (tid >= off) ? sm[tid - off] : 0;
        __syncthreads();
        sm[tid] += t;
        __syncthreads();
    }
    int excl = sm[tid] - v;
    if (tid < NSC) {
        chunkStart[tid] = excl;
        chunkCur[tid * 32] = excl;
    }
    if (tid == 0) chunkStart[NSC] = E;
}

// --------------------- CSR stage 3: bucket into staging --------------------
__global__ __launch_bounds__(512) void k_bucket(const int* __restrict__ src,
                                                const int* __restrict__ tgt,
                                                const float* __restrict__ ew,
                                                int* __restrict__ chunkCur,
                                                unsigned int* __restrict__ st_pw,
                                                unsigned char* __restrict__ st_t8,
                                                int E) {
    __shared__ int cnt[512];
    __shared__ int rk[512];
    __shared__ int bbase[512];
    const int tid = threadIdx.x;
    cnt[tid] = 0;
    rk[tid] = 0;
    __syncthreads();

    int t16[16];
    unsigned int p16[16];
#pragma unroll
    for (int r = 0; r < 4; r++) {
        int e = blockIdx.x * 8192 + r * 2048 + tid * 4;
        if (e + 3 < E) {
            int4 tv = *(const int4*)&tgt[e];
            int4 sv = *(const int4*)&src[e];
            float4 wv = *(const float4*)&ew[e];
            t16[r * 4 + 0] = tv.x; t16[r * 4 + 1] = tv.y;
            t16[r * 4 + 2] = tv.z; t16[r * 4 + 3] = tv.w;
            p16[r * 4 + 0] = ((unsigned int)f2bf(wv.x) << 17) | (unsigned int)sv.x;
            p16[r * 4 + 1] = ((unsigned int)f2bf(wv.y) << 17) | (unsigned int)sv.y;
            p16[r * 4 + 2] = ((unsigned int)f2bf(wv.z) << 17) | (unsigned int)sv.z;
            p16[r * 4 + 3] = ((unsigned int)f2bf(wv.w) << 17) | (unsigned int)sv.w;
        } else {
            for (int j = 0; j < 4; j++) {
                int ee = e + j;
                t16[r * 4 + j] = (ee < E) ? tgt[ee] : -1;
                p16[r * 4 + j] = (ee < E)
                    ? (((unsigned int)f2bf(ew[ee]) << 17) | (unsigned int)src[ee])
                    : 0u;
            }
        }
    }
#pragma unroll
    for (int j = 0; j < 16; j++)
        if (t16[j] >= 0) atomicAdd(&cnt[t16[j] >> SC_SHIFT], 1);
    __syncthreads();
    {
        int c = cnt[tid];
        bbase[tid] = c ? atomicAdd(&chunkCur[tid * 32], c) : 0;
    }
    __syncthreads();
#pragma unroll
    for (int j = 0; j < 16; j++) {
        if (t16[j] >= 0) {
            int c = t16[j] >> SC_SHIFT;
            int pos = bbase[c] + atomicAdd(&rk[c], 1);
            st_pw[pos] = p16[j];
            st_t8[pos] = (unsigned char)(t16[j] & (SC_NODES - 1));
        }
    }
}

// --------------------- CSR stage 4: per-bucket sort ------------------------
__global__ __launch_bounds__(256) void k_fill2(const unsigned int* __restrict__ st_pw,
                                               const unsigned char* __restrict__ st_t8,
                                               const int* __restrict__ chunkStart,
                                               int* __restrict__ rowptr,
                                               unsigned int* __restrict__ perm,
                                               int N, int E, int NSC) {
    __shared__ int lhist[SC_NODES];
    __shared__ int lcur[SC_NODES];
    __shared__ unsigned int ledge[FILL_CAP];
    const int tid = threadIdx.x;
    const int b = blockIdx.x;
    const int n0 = b << SC_SHIFT;
    const int nlocal = min(SC_NODES, N - n0);
    const int sstart = chunkStart[b];
    const int send = chunkStart[b + 1];
    const int cnt = send - sstart;

    lhist[tid] = 0;
    __syncthreads();
    for (int e = sstart + tid; e < send; e += 256)
        atomicAdd(&lhist[st_t8[e]], 1);
    __syncthreads();
    int v = lhist[tid];
    __syncthreads();
    lhist[tid] = v;
    __syncthreads();
    for (int off = 1; off < 256; off <<= 1) {
        int t = (tid >= off) ? lhist[tid - off] : 0;
        __syncthreads();
        lhist[tid] += t;
        __syncthreads();
    }
    int excl = lhist[tid] - v;
    if (tid < nlocal) rowptr[n0 + tid] = sstart + excl;
    if (b == NSC - 1 && tid == 0) rowptr[N] = E;
    lcur[tid] = excl;
    __syncthreads();

    if (cnt <= FILL_CAP) {
        for (int e = sstart + tid; e < send; e += 256) {
            int lt = st_t8[e];
            int pos = atomicAdd(&lcur[lt], 1);
            ledge[pos] = st_pw[e];
        }
        __syncthreads();
        for (int i = tid; i < cnt; i += 256) perm[sstart + i] = ledge[i];
    } else {
        for (int e = sstart + tid; e < send; e += 256) {
            int lt = st_t8[e];
            int pos = atomicAdd(&lcur[lt], 1);
            perm[sstart + pos] = st_pw[e];
        }
    }
}

// ----------------------------- weight prep --------------------------------
__global__ __launch_bounds__(256) void k_wtrans_all(
    const float* __restrict__ W0, const float* __restrict__ W1,
    const float* __restrict__ W2, const float* __restrict__ W3,
    unsigned short* __restrict__ Wt0, unsigned short* __restrict__ Wt1,
    unsigned short* __restrict__ Wt2, unsigned short* __restrict__ Wt3,
    int* __restrict__ chunkTot) {
    int idx = blockIdx.x * 256 + threadIdx.x;
    if (idx < 512) chunkTot[idx] = 0;
    if (idx < 32768) {
        int c = idx >> 8, k = idx & 255;
        Wt0[idx] = f2bf(W0[k * 128 + c]);
    } else if (idx < 49152) {
        int i = idx - 32768;
        int c = i >> 7, k = i & 127;
        Wt1[i] = f2bf(W1[k * 128 + c]);
    } else if (idx < 65536) {
        int i = idx - 49152;
        int c = i >> 7, k = i & 127;
        Wt2[i] = f2bf(W2[k * 128 + c]);
    } else if (idx < 71680) {
        int i = idx - 65536;
        int c = i >> 7, k = i & 127;
        Wt3[i] = (c < 40) ? f2bf(W3[k * 40 + c]) : 0;
    }
}

// ---------------------------------------------------------------------------
// MFMA GEMM: C[N,128](bf16) = A[N,K] @ Wt[128][K] + b. 128x128/block.
// Swapped operands: D = Wt_frag x X_frag -> lane holds C[row=l15][4 consecutive
// cols quad*4+i] per c-tile -> uint2 stores. Register-prefetch K pipeline.
// ---------------------------------------------------------------------------
template <int K, int AF32>
__global__ __launch_bounds__(256) void k_gemm_mfma(const void* __restrict__ Av,
                                                   const unsigned short* __restrict__ Wt,
                                                   const float* __restrict__ bias,
                                                   unsigned short* __restrict__ C, int N) {
    __shared__ unsigned short As[128 * 40];
    __shared__ unsigned short Bs[128 * 40];
    __shared__ float bsh[128];
    const unsigned short* A16 = (const unsigned short*)Av;
    const float* A32 = (const float*)Av;
    const int tid = threadIdx.x;
    const int wave = tid >> 6, lane = tid & 63;
    const int quad = lane >> 4, l15 = lane & 15;
    const int rowBase = blockIdx.x * 128;

    if (tid < 128) bsh[tid] = bias[tid];

    // staging geometry: chunk t = i*256+tid -> r=t>>2 (row), kc=t&3 (16B col)
    const int r0 = tid >> 2, kc0 = tid & 3;
    const int r1 = (256 + tid) >> 2, kc1 = kc0;  // r1 = r0 + 64
    int rg0 = rowBase + r0; rg0 = rg0 < N ? rg0 : N - 1;
    int rg1 = rowBase + r1; rg1 = rg1 < N ? rg1 : N - 1;

    uint4 pa[2], pb[2];
    auto load_step = [&](int k0) {
        if (AF32) {
            float4 f0 = *(const float4*)&A32[(size_t)rg0 * K + k0 + kc0 * 8];
            float4 f1 = *(const float4*)&A32[(size_t)rg0 * K + k0 + kc0 * 8 + 4];
            pa[0].x = packbf(f0.x, f0.y); pa[0].y = packbf(f0.z, f0.w);
            pa[0].z = packbf(f1.x, f1.y); pa[0].w = packbf(f1.z, f1.w);
            float4 g0 = *(const float4*)&A32[(size_t)rg1 * K + k0 + kc1 * 8];
            float4 g1 = *(const float4*)&A32[(size_t)rg1 * K + k0 + kc1 * 8 + 4];
            pa[1].x = packbf(g0.x, g0.y); pa[1].y = packbf(g0.z, g0.w);
            pa[1].z = packbf(g1.x, g1.y); pa[1].w = packbf(g1.z, g1.w);
        } else {
            pa[0] = *(const uint4*)&A16[(size_t)rg0 * K + k0 + kc0 * 8];
            pa[1] = *(const uint4*)&A16[(size_t)rg1 * K + k0 + kc1 * 8];
        }
        pb[0] = *(const uint4*)&Wt[(size_t)r0 * K + k0 + kc0 * 8];
        pb[1] = *(const uint4*)&Wt[(size_t)r1 * K + k0 + kc1 * 8];
    };

    const float4v z = {0.f, 0.f, 0.f, 0.f};
    float4v acc[2][8];
#pragma unroll
    for (int i = 0; i < 2; i++)
#pragma unroll
        for (int j = 0; j < 8; j++) acc[i][j] = z;

    load_step(0);
    for (int k0 = 0; k0 < K; k0 += 32) {
        *(uint4*)&As[r0 * 40 + kc0 * 8] = pa[0];
        *(uint4*)&As[r1 * 40 + kc1 * 8] = pa[1];
        *(uint4*)&Bs[r0 * 40 + kc0 * 8] = pb[0];
        *(uint4*)&Bs[r1 * 40 + kc1 * 8] = pb[1];
        __syncthreads();
        if (k0 + 32 < K) load_step(k0 + 32);  // prefetch overlaps compute

        short8 a0 = *(const short8*)&As[(wave * 32 + l15) * 40 + quad * 8];
        short8 a1 = *(const short8*)&As[(wave * 32 + 16 + l15) * 40 + quad * 8];
#pragma unroll
        for (int c = 0; c < 8; c++) {
            short8 b = *(const short8*)&Bs[(c * 16 + l15) * 40 + quad * 8];
            // swapped: A-op = Wt frag, B-op = X frag  =>  D = C^T tile
            acc[0][c] = __builtin_amdgcn_mfma_f32_16x16x32_bf16(b, a0, acc[0][c], 0, 0, 0);
            acc[1][c] = __builtin_amdgcn_mfma_f32_16x16x32_bf16(b, a1, acc[1][c], 0, 0, 0);
        }
        __syncthreads();
    }

    // lane holds C[row = rowBase+wave*32+rt*16+l15][cols c*16+quad*4 .. +3]
#pragma unroll
    for (int rt = 0; rt < 2; rt++) {
        int row = rowBase + wave * 32 + rt * 16 + l15;
        if (row < N) {
#pragma unroll
            for (int c = 0; c < 8; c++) {
                int colBase = c * 16 + quad * 4;
                float4 bv = *(const float4*)&bsh[colBase];
                uint2 o;
                o.x = packbf(acc[rt][c][0] + bv.x, acc[rt][c][1] + bv.y);
                o.y = packbf(acc[rt][c][2] + bv.z, acc[rt][c][3] + bv.w);
                *(uint2*)&C[(size_t)row * 128 + colBase] = o;
            }
        }
    }
}

// MFMA gemm40: H40[N,64-stride](bf16) = A[N,128](bf16) @ Wt3[48][128] + b3.
// Swapped operands + uint2 stores (pad cols 40..47 written, harmless).
__global__ __launch_bounds__(256) void k_gemm40_mfma(const unsigned short* __restrict__ A,
                                                     const unsigned short* __restrict__ Wt3,
                                                     const float* __restrict__ bias,
                                                     unsigned short* __restrict__ C, int N) {
    __shared__ unsigned short As[128 * 40];
    __shared__ unsigned short Bs[48 * 136];
    __shared__ float bsh[48];
    const int tid = threadIdx.x;
    const int wave = tid >> 6, lane = tid & 63;
    const int quad = lane >> 4, l15 = lane & 15;
    const int rowBase = blockIdx.x * 128;

    if (tid < 48) bsh[tid] = (tid < 40) ? bias[tid] : 0.f;
    for (int t = tid; t < 48 * 16; t += 256) {
        int r = t >> 4, kc = t & 15;
        uint4 v = *(const uint4*)&Wt3[r * 128 + kc * 8];
        *(uint4*)&Bs[r * 136 + kc * 8] = v;
    }

    const int r0 = tid >> 2, kc0 = tid & 3;
    const int r1 = r0 + 64;
    int rg0 = rowBase + r0; rg0 = rg0 < N ? rg0 : N - 1;
    int rg1 = rowBase + r1; rg1 = rg1 < N ? rg1 : N - 1;

    uint4 pa[2];
    auto load_step = [&](int k0) {
        pa[0] = *(const uint4*)&A[(size_t)rg0 * 128 + k0 + kc0 * 8];
        pa[1] = *(const uint4*)&A[(size_t)rg1 * 128 + k0 + kc0 * 8];
    };

    const float4v z = {0.f, 0.f, 0.f, 0.f};
    float4v acc[2][3];
#pragma unroll
    for (int i = 0; i < 2; i++)
#pragma unroll
        for (int j = 0; j < 3; j++) acc[i][j] = z;

    load_step(0);
    for (int k0 = 0; k0 < 128; k0 += 32) {
        *(uint4*)&As[r0 * 40 + kc0 * 8] = pa[0];
        *(uint4*)&As[r1 * 40 + kc0 * 8] = pa[1];
        __syncthreads();
        if (k0 + 32 < 128) load_step(k0 + 32);

        short8 a0 = *(const short8*)&As[(wave * 32 + l15) * 40 + quad * 8];
        short8 a1 = *(const short8*)&As[(wave * 32 + 16 + l15) * 40 + quad * 8];
#pragma unroll
        for (int c = 0; c < 3; c++) {
            short8 b = *(const short8*)&Bs[(c * 16 + l15) * 136 + k0 + quad * 8];
            acc[0][c] = __builtin_amdgcn_mfma_f32_16x16x32_bf16(b, a0, acc[0][c], 0, 0, 0);
            acc[1][c] = __builtin_amdgcn_mfma_f32_16x16x32_bf16(b, a1, acc[1][c], 0, 0, 0);
        }
        __syncthreads();
    }

#pragma unroll
    for (int rt = 0; rt < 2; rt++) {
        int row = rowBase + wave * 32 + rt * 16 + l15;
        if (row < N) {
#pragma unroll
            for (int c = 0; c < 3; c++) {
                int colBase = c * 16 + quad * 4;
                float4 bv = *(const float4*)&bsh[colBase];
                uint2 o;
                o.x = packbf(acc[rt][c][0] + bv.x, acc[rt][c][1] + bv.y);
                o.y = packbf(acc[rt][c][2] + bv.z, acc[rt][c][3] + bv.w);
                *(uint2*)&C[(size_t)row * 64 + colBase] = o;
            }
        }
    }
}

// ---------------------------------------------------------------------------
// Pull aggregation F=128: one wave/node, quarter-wave per edge (packed perm).
// ---------------------------------------------------------------------------
__global__ __launch_bounds__(256) void k_agg128(const unsigned short* __restrict__ h,
                                                const int* __restrict__ rowptr,
                                                const unsigned int* __restrict__ perm,
                                                const unsigned short* __restrict__ resid,
                                                unsigned short* __restrict__ out, int N) {
    int node = (blockIdx.x * 256 + threadIdx.x) >> 6;
    if (node >= N) return;
    const int lane = threadIdx.x & 63;
    const int g = lane >> 4, l = lane & 15;
    const int beg = rowptr[node], end = rowptr[node + 1];
    const int last = end - 1;

    float acc[8] = {};
    for (int base = beg; base < end; base += 16) {
        int e0 = base + g, e1 = base + 4 + g, e2 = base + 8 + g, e3 = base + 12 + g;
        unsigned int p0 = perm[e0 <= last ? e0 : last];
        unsigned int p1 = perm[e1 <= last ? e1 : last];
        unsigned int p2 = perm[e2 <= last ? e2 : last];
        unsigned int p3 = perm[e3 <= last ? e3 : last];
        uint4 a0 = *(const uint4*)&h[(size_t)(p0 & SRC_MASK) * 128 + l * 8];
        uint4 a1 = *(const uint4*)&h[(size_t)(p1 & SRC_MASK) * 128 + l * 8];
        uint4 a2 = *(const uint4*)&h[(size_t)(p2 & SRC_MASK) * 128 + l * 8];
        uint4 a3 = *(const uint4*)&h[(size_t)(p3 & SRC_MASK) * 128 + l * 8];
        float w0 = e0 <= last ? pw_w(p0) : 0.f;
        float w1 = e1 <= last ? pw_w(p1) : 0.f;
        float w2 = e2 <= last ? pw_w(p2) : 0.f;
        float w3 = e3 <= last ? pw_w(p3) : 0.f;
        acc8(acc, a0, w0);
        acc8(acc, a1, w1);
        acc8(acc, a2, w2);
        acc8(acc, a3, w3);
    }

#pragma unroll
    for (int i = 0; i < 8; i++) {
        acc[i] += __shfl_xor(acc[i], 16);
        acc[i] += __shfl_xor(acc[i], 32);
    }

    if (g == 0) {
#pragma unroll
        for (int i = 0; i < 8; i++) acc[i] = fmaxf(acc[i], 0.f);
        if (resid) {
            uint4 rv = *(const uint4*)&resid[(size_t)node * 128 + l * 8];
            acc[0] += bf2f_lo(rv.x); acc[1] += bf2f_hi(rv.x);
            acc[2] += bf2f_lo(rv.y); acc[3] += bf2f_hi(rv.y);
            acc[4] += bf2f_lo(rv.z); acc[5] += bf2f_hi(rv.z);
            acc[6] += bf2f_lo(rv.w); acc[7] += bf2f_hi(rv.w);
        }
        uint4 o;
        o.x = packbf(acc[0], acc[1]);
        o.y = packbf(acc[2], acc[3]);
        o.z = packbf(acc[4], acc[5]);
        o.w = packbf(acc[6], acc[7]);
        *(uint4*)&out[(size_t)node * 128 + l * 8] = o;
    }
}

// ---------------------------------------------------------------------------
// Final layer: F=40 gather, 16-lane groups, row-line-confined; fused lsm.
// ---------------------------------------------------------------------------
__global__ __launch_bounds__(256) void k_agg40_lsm(const unsigned short* __restrict__ h,
                                                   const int* __restrict__ rowptr,
                                                   const unsigned int* __restrict__ perm,
                                                   float* __restrict__ out, int N) {
    int node = (blockIdx.x * 256 + threadIdx.x) >> 6;
    if (node >= N) return;
    const int lane = threadIdx.x & 63;
    const int g = lane >> 4, l = lane & 15;
    const int beg = rowptr[node], end = rowptr[node + 1];
    const int last = end - 1;
    const int lc = l < 10 ? l : 0;

    float acc[4] = {};
    for (int base = beg; base < end; base += 16) {
        int e0 = base + g, e1 = base + 4 + g, e2 = base + 8 + g, e3 = base + 12 + g;
        unsigned int p0 = perm[e0 <= last ? e0 : last];
        unsigned int p1 = perm[e1 <= last ? e1 : last];
        unsigned int p2 = perm[e2 <= last ? e2 : last];
        unsigned int p3 = perm[e3 <= last ? e3 : last];
        uint2 a0 = *(const uint2*)&h[(size_t)(p0 & SRC_MASK) * 64 + lc * 4];
        uint2 a1 = *(const uint2*)&h[(size_t)(p1 & SRC_MASK) * 64 + lc * 4];
        uint2 a2 = *(const uint2*)&h[(size_t)(p2 & SRC_MASK) * 64 + lc * 4];
        uint2 a3 = *(const uint2*)&h[(size_t)(p3 & SRC_MASK) * 64 + lc * 4];
        float w0 = e0 <= last ? pw_w(p0) : 0.f;
        float w1 = e1 <= last ? pw_w(p1) : 0.f;
        float w2 = e2 <= last ? pw_w(p2) : 0.f;
        float w3 = e3 <= last ? pw_w(p3) : 0.f;
        acc4(acc, a0, w0);
        acc4(acc, a1, w1);
        acc4(acc, a2, w2);
        acc4(acc, a3, w3);
    }
#pragma unroll
    for (int i = 0; i < 4; i++) {
        acc[i] += __shfl_xor(acc[i], 16);
        acc[i] += __shfl_xor(acc[i], 32);
    }

    bool vf = l < 10;
    float m = vf ? fmaxf(fmaxf(acc[0], acc[1]), fmaxf(acc[2], acc[3]))
                 : -__builtin_inff();
#pragma unroll
    for (int off = 1; off < 16; off <<= 1) m = fmaxf(m, __shfl_xor(m, off));
    float s = vf ? (expf(acc[0] - m) + expf(acc[1] - m) +
                    expf(acc[2] - m) + expf(acc[3] - m))
                 : 0.f;
#pragma unroll
    for (int off = 1; off < 16; off <<= 1) s += __shfl_xor(s, off);
    float ls = m + logf(s);
    if (g == 0 && vf) {
        float4 o = make_float4(acc[0] - ls, acc[1] - ls, acc[2] - ls, acc[3] - ls);
        *(float4*)&out[(size_t)node * 40 + l * 4] = o;
    }
}

extern "C" void kernel_launch(void* const* d_in, const int* in_sizes, int n_in,
                              void* d_out, int out_size, void* d_ws, size_t ws_size,
                              hipStream_t stream) {
    const float* x  = (const float*)d_in[0];
    const int*   src = (const int*)d_in[1];
    const int*   tgt = (const int*)d_in[2];
    const float* ew  = (const float*)d_in[3];
    const float* W0 = (const float*)d_in[4];
    const float* b0 = (const float*)d_in[5];
    const float* W1 = (const float*)d_in[6];
    const float* b1 = (const float*)d_in[7];
    const float* W2 = (const float*)d_in[8];
    const float* b2 = (const float*)d_in[9];
    const float* W3 = (const float*)d_in[10];
    const float* b3 = (const float*)d_in[11];

    const int N = in_sizes[0] / 256;
    const int E = in_sizes[1];
    const int NSC = (N + SC_NODES - 1) >> SC_SHIFT;

    char* ws = (char*)d_ws;
    size_t off = 0;
    auto alloc = [&](size_t bytes) -> void* {
        void* p = ws + off;
        off = (off + bytes + 255) & ~(size_t)255;
        return p;
    };
    unsigned short* XCb = (unsigned short*)alloc((size_t)N * 128 * 2);
    size_t hbytes = (size_t)N * 128 * 2;
    size_t sbytes = (size_t)E * 5 + 256;
    char* hbuf = (char*)alloc(hbytes > sbytes ? hbytes : sbytes);
    unsigned short* Hb = (unsigned short*)hbuf;
    unsigned int* st_pw = (unsigned int*)hbuf;
    unsigned char* st_t8 = (unsigned char*)(hbuf + (size_t)E * 4);
    char* buf1 = (char*)alloc((size_t)N * 128 * 2);
    unsigned short* XAb  = (unsigned short*)buf1;
    unsigned short* H40b = (unsigned short*)buf1;
    unsigned short* XBb  = (unsigned short*)alloc((size_t)N * 128 * 2);
    int*   rowptr    = (int*)alloc((size_t)(N + 1) * 4);
    int*   chunkTot  = (int*)alloc(512 * 4);
    int*   chunkStart= (int*)alloc(520 * 4);
    int*   chunkCur  = (int*)alloc(512 * 32 * 4);
    unsigned int* perm = (unsigned int*)alloc((size_t)E * 4);
    unsigned short* Wt0 = (unsigned short*)alloc(256 * 128 * 2);
    unsigned short* Wt1 = (unsigned short*)alloc(128 * 128 * 2);
    unsigned short* Wt2 = (unsigned short*)alloc(128 * 128 * 2);
    unsigned short* Wt3 = (unsigned short*)alloc(48 * 128 * 2);
    (void)ws_size;

    float* logits = (float*)d_out;

    k_wtrans_all<<<(71680 + 255) / 256, 256, 0, stream>>>(W0, W1, W2, W3,
                                                          Wt0, Wt1, Wt2, Wt3,
                                                          chunkTot);
    k_count<<<(E + 4095) / 4096, 256, 0, stream>>>(tgt, chunkTot, E, NSC);
    k_scanB<<<1, 512, 0, stream>>>(chunkTot, chunkStart, chunkCur, E, NSC);
    k_bucket<<<(E + 8191) / 8192, 512, 0, stream>>>(src, tgt, ew, chunkCur,
                                                    st_pw, st_t8, E);
    k_fill2<<<NSC, 256, 0, stream>>>(st_pw, st_t8, chunkStart, rowptr, perm,
                                     N, E, NSC);

    const int gGemm = (N + 127) / 128;
    const int gWave = (N + 3) / 4;

    // L0 (reads fp32 x directly)
    k_gemm_mfma<256, 1><<<gGemm, 256, 0, stream>>>(x, Wt0, b0, Hb, N);
    k_agg128<<<gWave, 256, 0, stream>>>(Hb, rowptr, perm, nullptr, XAb, N);
    // L1
    k_gemm_mfma<128, 0><<<gGemm, 256, 0, stream>>>(XAb, Wt1, b1, Hb, N);
    k_agg128<<<gWave, 256, 0, stream>>>(Hb, rowptr, perm, nullptr, XBb, N);
    // L2 (+residual XAb) -> XCb
    k_gemm_mfma<128, 0><<<gGemm, 256, 0, stream>>>(XBb, Wt2, b2, Hb, N);
    k_agg128<<<gWave, 256, 0, stream>>>(Hb, rowptr, perm, XAb, XCb, N);
    // L3
    k_gemm40_mfma<<<gGemm, 256, 0, stream>>>(XCb, Wt3, b3, H40b, N);
    k_agg40_lsm<<<gWave, 256, 0, stream>>>(H40b, rowptr, perm, logits, N);
}

// Round 9
// 490.644 us; speedup vs baseline: 1.1173x; 1.1173x over previous
//
#include <hip/hip_runtime.h>
#include <hip/hip_bf16.h>

// ---------------------------------------------------------------------------
// RESK2 4-layer GCN on MI355X — round 9.
//  GEMMs: 64-row tiles (2x blocks, ~6/CU occupancy), swapped-operand MFMA,
//  LDS-staged epilogue -> full-line coalesced uint4 stores (no RMW).
//  CSR + agg kernels unchanged from round 7/8.
// ---------------------------------------------------------------------------

typedef __attribute__((ext_vector_type(8))) short short8;
typedef __attribute__((ext_vector_type(4))) float float4v;

#define SC_SHIFT 8              // 256 nodes per sub-chunk
#define SC_NODES 256
#define FILL_CAP 12288
#define SRC_MASK 0x1FFFF        // 17 bits (N=100000 < 131072)

static __device__ __forceinline__ float bf2f_lo(unsigned int v) {
    return __uint_as_float(v << 16);
}
static __device__ __forceinline__ float bf2f_hi(unsigned int v) {
    return __uint_as_float(v & 0xffff0000u);
}
static __device__ __forceinline__ unsigned short f2bf(float f) {
    unsigned int u = __float_as_uint(f);
    u = (u + 0x7fffu + ((u >> 16) & 1u)) >> 16;  // RNE
    return (unsigned short)u;
}
static __device__ __forceinline__ unsigned int packbf(float a, float b) {
    return (unsigned int)f2bf(a) | ((unsigned int)f2bf(b) << 16);
}
static __device__ __forceinline__ float pw_w(unsigned int pe) {
    return __uint_as_float((pe >> 17) << 16);
}

static __device__ __forceinline__ void acc8(float* acc, uint4 v, float wt) {
    acc[0] = fmaf(bf2f_lo(v.x), wt, acc[0]);
    acc[1] = fmaf(bf2f_hi(v.x), wt, acc[1]);
    acc[2] = fmaf(bf2f_lo(v.y), wt, acc[2]);
    acc[3] = fmaf(bf2f_hi(v.y), wt, acc[3]);
    acc[4] = fmaf(bf2f_lo(v.z), wt, acc[4]);
    acc[5] = fmaf(bf2f_hi(v.z), wt, acc[5]);
    acc[6] = fmaf(bf2f_lo(v.w), wt, acc[6]);
    acc[7] = fmaf(bf2f_hi(v.w), wt, acc[7]);
}
static __device__ __forceinline__ void acc4(float* acc, uint2 v, float wt) {
    acc[0] = fmaf(bf2f_lo(v.x), wt, acc[0]);
    acc[1] = fmaf(bf2f_hi(v.x), wt, acc[1]);
    acc[2] = fmaf(bf2f_lo(v.y), wt, acc[2]);
    acc[3] = fmaf(bf2f_hi(v.y), wt, acc[3]);
}

// --------------------- CSR stage 1: bucket histogram -----------------------
__global__ __launch_bounds__(256) void k_count(const int* __restrict__ tgt,
                                               int* __restrict__ chunkTot,
                                               int E, int NSC) {
    __shared__ int hist[512];
    const int tid = threadIdx.x;
    hist[tid] = 0;
    hist[tid + 256] = 0;
    __syncthreads();
#pragma unroll
    for (int r = 0; r < 4; r++) {
        int e = blockIdx.x * 4096 + r * 1024 + tid * 4;
        if (e + 3 < E) {
            int4 tv = *(const int4*)&tgt[e];
            atomicAdd(&hist[tv.x >> SC_SHIFT], 1);
            atomicAdd(&hist[tv.y >> SC_SHIFT], 1);
            atomicAdd(&hist[tv.z >> SC_SHIFT], 1);
            atomicAdd(&hist[tv.w >> SC_SHIFT], 1);
        } else {
            for (int j = 0; j < 4; j++)
                if (e + j < E) atomicAdd(&hist[tgt[e + j] >> SC_SHIFT], 1);
        }
    }
    __syncthreads();
    for (int i = tid; i < NSC; i += 256) {
        int c = hist[i];
        if (c) atomicAdd(&chunkTot[i], c);
    }
}

// --------------------- CSR stage 2: bucket prefix scan ---------------------
__global__ __launch_bounds__(512) void k_scanB(const int* __restrict__ chunkTot,
                                               int* __restrict__ chunkStart,
                                               int* __restrict__ chunkCur,
                                               int E, int NSC) {
    __shared__ int sm[512];
    const int tid = threadIdx.x;
    int v = (tid < NSC) ? chunkTot[tid] : 0;
    sm[tid] = v;
    __syncthreads();
    for (int off = 1; off < 512; off <<= 1) {
        int t = (tid >= off) ? sm[tid - off] : 0;
        __syncthreads();
        sm[tid] += t;
        __syncthreads();
    }
    int excl = sm[tid] - v;
    if (tid < NSC) {
        chunkStart[tid] = excl;
        chunkCur[tid * 32] = excl;
    }
    if (tid == 0) chunkStart[NSC] = E;
}

// --------------------- CSR stage 3: bucket into staging --------------------
__global__ __launch_bounds__(512) void k_bucket(const int* __restrict__ src,
                                                const int* __restrict__ tgt,
                                                const float* __restrict__ ew,
                                                int* __restrict__ chunkCur,
                                                unsigned int* __restrict__ st_pw,
                                                unsigned char* __restrict__ st_t8,
                                                int E) {
    __shared__ int cnt[512];
    __shared__ int rk[512];
    __shared__ int bbase[512];
    const int tid = threadIdx.x;
    cnt[tid] = 0;
    rk[tid] = 0;
    __syncthreads();

    int t16[16];
    unsigned int p16[16];
#pragma unroll
    for (int r = 0; r < 4; r++) {
        int e = blockIdx.x * 8192 + r * 2048 + tid * 4;
        if (e + 3 < E) {
            int4 tv = *(const int4*)&tgt[e];
            int4 sv = *(const int4*)&src[e];
            float4 wv = *(const float4*)&ew[e];
            t16[r * 4 + 0] = tv.x; t16[r * 4 + 1] = tv.y;
            t16[r * 4 + 2] = tv.z; t16[r * 4 + 3] = tv.w;
            p16[r * 4 + 0] = ((unsigned int)f2bf(wv.x) << 17) | (unsigned int)sv.x;
            p16[r * 4 + 1] = ((unsigned int)f2bf(wv.y) << 17) | (unsigned int)sv.y;
            p16[r * 4 + 2] = ((unsigned int)f2bf(wv.z) << 17) | (unsigned int)sv.z;
            p16[r * 4 + 3] = ((unsigned int)f2bf(wv.w) << 17) | (unsigned int)sv.w;
        } else {
            for (int j = 0; j < 4; j++) {
                int ee = e + j;
                t16[r * 4 + j] = (ee < E) ? tgt[ee] : -1;
                p16[r * 4 + j] = (ee < E)
                    ? (((unsigned int)f2bf(ew[ee]) << 17) | (unsigned int)src[ee])
                    : 0u;
            }
        }
    }
#pragma unroll
    for (int j = 0; j < 16; j++)
        if (t16[j] >= 0) atomicAdd(&cnt[t16[j] >> SC_SHIFT], 1);
    __syncthreads();
    {
        int c = cnt[tid];
        bbase[tid] = c ? atomicAdd(&chunkCur[tid * 32], c) : 0;
    }
    __syncthreads();
#pragma unroll
    for (int j = 0; j < 16; j++) {
        if (t16[j] >= 0) {
            int c = t16[j] >> SC_SHIFT;
            int pos = bbase[c] + atomicAdd(&rk[c], 1);
            st_pw[pos] = p16[j];
            st_t8[pos] = (unsigned char)(t16[j] & (SC_NODES - 1));
        }
    }
}

// --------------------- CSR stage 4: per-bucket sort ------------------------
__global__ __launch_bounds__(256) void k_fill2(const unsigned int* __restrict__ st_pw,
                                               const unsigned char* __restrict__ st_t8,
                                               const int* __restrict__ chunkStart,
                                               int* __restrict__ rowptr,
                                               unsigned int* __restrict__ perm,
                                               int N, int E, int NSC) {
    __shared__ int lhist[SC_NODES];
    __shared__ int lcur[SC_NODES];
    __shared__ unsigned int ledge[FILL_CAP];
    const int tid = threadIdx.x;
    const int b = blockIdx.x;
    const int n0 = b << SC_SHIFT;
    const int nlocal = min(SC_NODES, N - n0);
    const int sstart = chunkStart[b];
    const int send = chunkStart[b + 1];
    const int cnt = send - sstart;

    lhist[tid] = 0;
    __syncthreads();
    for (int e = sstart + tid; e < send; e += 256)
        atomicAdd(&lhist[st_t8[e]], 1);
    __syncthreads();
    int v = lhist[tid];
    __syncthreads();
    lhist[tid] = v;
    __syncthreads();
    for (int off = 1; off < 256; off <<= 1) {
        int t = (tid >= off) ? lhist[tid - off] : 0;
        __syncthreads();
        lhist[tid] += t;
        __syncthreads();
    }
    int excl = lhist[tid] - v;
    if (tid < nlocal) rowptr[n0 + tid] = sstart + excl;
    if (b == NSC - 1 && tid == 0) rowptr[N] = E;
    lcur[tid] = excl;
    __syncthreads();

    if (cnt <= FILL_CAP) {
        for (int e = sstart + tid; e < send; e += 256) {
            int lt = st_t8[e];
            int pos = atomicAdd(&lcur[lt], 1);
            ledge[pos] = st_pw[e];
        }
        __syncthreads();
        for (int i = tid; i < cnt; i += 256) perm[sstart + i] = ledge[i];
    } else {
        for (int e = sstart + tid; e < send; e += 256) {
            int lt = st_t8[e];
            int pos = atomicAdd(&lcur[lt], 1);
            perm[sstart + pos] = st_pw[e];
        }
    }
}

// ----------------------------- weight prep --------------------------------
__global__ __launch_bounds__(256) void k_wtrans_all(
    const float* __restrict__ W0, const float* __restrict__ W1,
    const float* __restrict__ W2, const float* __restrict__ W3,
    unsigned short* __restrict__ Wt0, unsigned short* __restrict__ Wt1,
    unsigned short* __restrict__ Wt2, unsigned short* __restrict__ Wt3,
    int* __restrict__ chunkTot) {
    int idx = blockIdx.x * 256 + threadIdx.x;
    if (idx < 512) chunkTot[idx] = 0;
    if (idx < 32768) {
        int c = idx >> 8, k = idx & 255;
        Wt0[idx] = f2bf(W0[k * 128 + c]);
    } else if (idx < 49152) {
        int i = idx - 32768;
        int c = i >> 7, k = i & 127;
        Wt1[i] = f2bf(W1[k * 128 + c]);
    } else if (idx < 65536) {
        int i = idx - 49152;
        int c = i >> 7, k = i & 127;
        Wt2[i] = f2bf(W2[k * 128 + c]);
    } else if (idx < 71680) {
        int i = idx - 65536;
        int c = i >> 7, k = i & 127;
        Wt3[i] = (c < 40) ? f2bf(W3[k * 40 + c]) : 0;
    }
}

// ---------------------------------------------------------------------------
// MFMA GEMM: C[N,128](bf16) = A[N,K] @ Wt[128][K] + b. 64x128 tile/block,
// 4 waves, wave = 16 rows x 128 cols. Swapped operands: lane holds
// C[row=l15][cols quad*4..+3] per c-tile. Epilogue staged through LDS ->
// full-line uint4 stores.
// ---------------------------------------------------------------------------
template <int K, int AF32>
__global__ __launch_bounds__(256) void k_gemm_mfma(const void* __restrict__ Av,
                                                   const unsigned short* __restrict__ Wt,
                                                   const float* __restrict__ bias,
                                                   unsigned short* __restrict__ C, int N) {
    __shared__ union {
        struct {
            unsigned short As[64 * 40];
            unsigned short Bs[128 * 40];
        } s;
        unsigned short Cs[64 * 136];  // epilogue staging, stride 136 (272B = 17x16B)
    } u;
    __shared__ float bsh[128];
    const unsigned short* A16 = (const unsigned short*)Av;
    const float* A32 = (const float*)Av;
    const int tid = threadIdx.x;
    const int wave = tid >> 6, lane = tid & 63;
    const int quad = lane >> 4, l15 = lane & 15;
    const int rowBase = blockIdx.x * 64;

    if (tid < 128) bsh[tid] = bias[tid];

    const int r0 = tid >> 2, kc0 = tid & 3;  // A: 64 rows x 4 chunks
    const int rB1 = r0, rB2 = r0 + 64;       // Wt: 128 rows
    int rg0 = rowBase + r0;
    rg0 = rg0 < N ? rg0 : N - 1;

    uint4 pa, pb0, pb1;
    auto load_step = [&](int k0) {
        if (AF32) {
            float4 f0 = *(const float4*)&A32[(size_t)rg0 * K + k0 + kc0 * 8];
            float4 f1 = *(const float4*)&A32[(size_t)rg0 * K + k0 + kc0 * 8 + 4];
            pa.x = packbf(f0.x, f0.y);
            pa.y = packbf(f0.z, f0.w);
            pa.z = packbf(f1.x, f1.y);
            pa.w = packbf(f1.z, f1.w);
        } else {
            pa = *(const uint4*)&A16[(size_t)rg0 * K + k0 + kc0 * 8];
        }
        pb0 = *(const uint4*)&Wt[(size_t)rB1 * K + k0 + kc0 * 8];
        pb1 = *(const uint4*)&Wt[(size_t)rB2 * K + k0 + kc0 * 8];
    };

    const float4v z = {0.f, 0.f, 0.f, 0.f};
    float4v acc[8];
#pragma unroll
    for (int j = 0; j < 8; j++) acc[j] = z;

    load_step(0);
    for (int k0 = 0; k0 < K; k0 += 32) {
        *(uint4*)&u.s.As[r0 * 40 + kc0 * 8] = pa;
        *(uint4*)&u.s.Bs[rB1 * 40 + kc0 * 8] = pb0;
        *(uint4*)&u.s.Bs[rB2 * 40 + kc0 * 8] = pb1;
        __syncthreads();
        if (k0 + 32 < K) load_step(k0 + 32);  // prefetch overlaps compute

        short8 a = *(const short8*)&u.s.As[(wave * 16 + l15) * 40 + quad * 8];
#pragma unroll
        for (int c = 0; c < 8; c++) {
            short8 b = *(const short8*)&u.s.Bs[(c * 16 + l15) * 40 + quad * 8];
            acc[c] = __builtin_amdgcn_mfma_f32_16x16x32_bf16(b, a, acc[c], 0, 0, 0);
        }
        __syncthreads();
    }

    // stage C tile (64x128 bf16) into LDS, then full-line stores
#pragma unroll
    for (int c = 0; c < 8; c++) {
        int colBase = c * 16 + quad * 4;
        float4 bv = *(const float4*)&bsh[colBase];
        uint2 o;
        o.x = packbf(acc[c][0] + bv.x, acc[c][1] + bv.y);
        o.y = packbf(acc[c][2] + bv.z, acc[c][3] + bv.w);
        *(uint2*)&u.Cs[(wave * 16 + l15) * 136 + colBase] = o;
    }
    __syncthreads();
#pragma unroll
    for (int i = 0; i < 4; i++) {
        int flat = i * 256 + tid;       // 0..1023 uint4s
        int row = flat >> 4, q = flat & 15;
        int grow = rowBase + row;
        if (grow < N) {
            uint4 v = *(const uint4*)&u.Cs[row * 136 + q * 8];
            *(uint4*)&C[(size_t)grow * 128 + q * 8] = v;
        }
    }
}

// MFMA gemm40: H40[N,64-stride](bf16) = A[N,128](bf16) @ Wt3[48][128] + b3.
// 64-row tile; cols 48..63 zero-filled -> full 128B-line rows.
__global__ __launch_bounds__(256) void k_gemm40_mfma(const unsigned short* __restrict__ A,
                                                     const unsigned short* __restrict__ Wt3,
                                                     const float* __restrict__ bias,
                                                     unsigned short* __restrict__ C, int N) {
    __shared__ union {
        struct {
            unsigned short As[64 * 40];
            unsigned short Bs[48 * 136];
        } s;
        unsigned short Cs[64 * 72];  // stride 72 shorts = 144B (9x16B)
    } u;
    __shared__ float bsh[64];
    const int tid = threadIdx.x;
    const int wave = tid >> 6, lane = tid & 63;
    const int quad = lane >> 4, l15 = lane & 15;
    const int rowBase = blockIdx.x * 64;

    if (tid < 64) bsh[tid] = (tid < 40) ? bias[tid] : 0.f;

    const int r0 = tid >> 2, kc0 = tid & 3;
    int rg0 = rowBase + r0;
    rg0 = rg0 < N ? rg0 : N - 1;

    // Bs3 staged once (survives the K loop)
    for (int t = tid; t < 48 * 16; t += 256) {
        int r = t >> 4, kc = t & 15;
        uint4 v = *(const uint4*)&Wt3[r * 128 + kc * 8];
        *(uint4*)&u.s.Bs[r * 136 + kc * 8] = v;
    }

    uint4 pa;
    auto load_step = [&](int k0) {
        pa = *(const uint4*)&A[(size_t)rg0 * 128 + k0 + kc0 * 8];
    };

    const float4v z = {0.f, 0.f, 0.f, 0.f};
    float4v acc[3];
#pragma unroll
    for (int j = 0; j < 3; j++) acc[j] = z;

    load_step(0);
    for (int k0 = 0; k0 < 128; k0 += 32) {
        *(uint4*)&u.s.As[r0 * 40 + kc0 * 8] = pa;
        __syncthreads();
        if (k0 + 32 < 128) load_step(k0 + 32);

        short8 a = *(const short8*)&u.s.As[(wave * 16 + l15) * 40 + quad * 8];
#pragma unroll
        for (int c = 0; c < 3; c++) {
            short8 b = *(const short8*)&u.s.Bs[(c * 16 + l15) * 136 + k0 + quad * 8];
            acc[c] = __builtin_amdgcn_mfma_f32_16x16x32_bf16(b, a, acc[c], 0, 0, 0);
        }
        __syncthreads();
    }

    // stage 64x64 (48 data + 16 zero cols) into LDS
#pragma unroll
    for (int c = 0; c < 4; c++) {
        int colBase = c * 16 + quad * 4;
        uint2 o;
        if (c < 3) {
            float4 bv = *(const float4*)&bsh[colBase];
            o.x = packbf(acc[c][0] + bv.x, acc[c][1] + bv.y);
            o.y = packbf(acc[c][2] + bv.z, acc[c][3] + bv.w);
        } else {
            o.x = 0u;
            o.y = 0u;
        }
        *(uint2*)&u.Cs[(wave * 16 + l15) * 72 + colBase] = o;
    }
    __syncthreads();
#pragma unroll
    for (int i = 0; i < 2; i++) {
        int flat = i * 256 + tid;       // 0..511 uint4s (64 rows x 8)
        int row = flat >> 3, q = flat & 7;
        int grow = rowBase + row;
        if (grow < N) {
            uint4 v = *(const uint4*)&u.Cs[row * 72 + q * 8];
            *(uint4*)&C[(size_t)grow * 64 + q * 8] = v;
        }
    }
}

// ---------------------------------------------------------------------------
// Pull aggregation F=128: one wave/node, quarter-wave per edge (packed perm).
// ---------------------------------------------------------------------------
__global__ __launch_bounds__(256) void k_agg128(const unsigned short* __restrict__ h,
                                                const int* __restrict__ rowptr,
                                                const unsigned int* __restrict__ perm,
                                                const unsigned short* __restrict__ resid,
                                                unsigned short* __restrict__ out, int N) {
    int node = (blockIdx.x * 256 + threadIdx.x) >> 6;
    if (node >= N) return;
    const int lane = threadIdx.x & 63;
    const int g = lane >> 4, l = lane & 15;
    const int beg = rowptr[node], end = rowptr[node + 1];
    const int last = end - 1;

    float acc[8] = {};
    for (int base = beg; base < end; base += 16) {
        int e0 = base + g, e1 = base + 4 + g, e2 = base + 8 + g, e3 = base + 12 + g;
        unsigned int p0 = perm[e0 <= last ? e0 : last];
        unsigned int p1 = perm[e1 <= last ? e1 : last];
        unsigned int p2 = perm[e2 <= last ? e2 : last];
        unsigned int p3 = perm[e3 <= last ? e3 : last];
        uint4 a0 = *(const uint4*)&h[(size_t)(p0 & SRC_MASK) * 128 + l * 8];
        uint4 a1 = *(const uint4*)&h[(size_t)(p1 & SRC_MASK) * 128 + l * 8];
        uint4 a2 = *(const uint4*)&h[(size_t)(p2 & SRC_MASK) * 128 + l * 8];
        uint4 a3 = *(const uint4*)&h[(size_t)(p3 & SRC_MASK) * 128 + l * 8];
        float w0 = e0 <= last ? pw_w(p0) : 0.f;
        float w1 = e1 <= last ? pw_w(p1) : 0.f;
        float w2 = e2 <= last ? pw_w(p2) : 0.f;
        float w3 = e3 <= last ? pw_w(p3) : 0.f;
        acc8(acc, a0, w0);
        acc8(acc, a1, w1);
        acc8(acc, a2, w2);
        acc8(acc, a3, w3);
    }

#pragma unroll
    for (int i = 0; i < 8; i++) {
        acc[i] += __shfl_xor(acc[i], 16);
        acc[i] += __shfl_xor(acc[i], 32);
    }

    if (g == 0) {
#pragma unroll
        for (int i = 0; i < 8; i++) acc[i] = fmaxf(acc[i], 0.f);
        if (resid) {
            uint4 rv = *(const uint4*)&resid[(size_t)node * 128 + l * 8];
            acc[0] += bf2f_lo(rv.x); acc[1] += bf2f_hi(rv.x);
            acc[2] += bf2f_lo(rv.y); acc[3] += bf2f_hi(rv.y);
            acc[4] += bf2f_lo(rv.z); acc[5] += bf2f_hi(rv.z);
            acc[6] += bf2f_lo(rv.w); acc[7] += bf2f_hi(rv.w);
        }
        uint4 o;
        o.x = packbf(acc[0], acc[1]);
        o.y = packbf(acc[2], acc[3]);
        o.z = packbf(acc[4], acc[5]);
        o.w = packbf(acc[6], acc[7]);
        *(uint4*)&out[(size_t)node * 128 + l * 8] = o;
    }
}

// ---------------------------------------------------------------------------
// Final layer: F=40 gather, 16-lane groups, row-line-confined; fused lsm.
// ---------------------------------------------------------------------------
__global__ __launch_bounds__(256) void k_agg40_lsm(const unsigned short* __restrict__ h,
                                                   const int* __restrict__ rowptr,
                                                   const unsigned int* __restrict__ perm,
                                                   float* __restrict__ out, int N) {
    int node = (blockIdx.x * 256 + threadIdx.x) >> 6;
    if (node >= N) return;
    const int lane = threadIdx.x & 63;
    const int g = lane >> 4, l = lane & 15;
    const int beg = rowptr[node], end = rowptr[node + 1];
    const int last = end - 1;
    const int lc = l < 10 ? l : 0;

    float acc[4] = {};
    for (int base = beg; base < end; base += 16) {
        int e0 = base + g, e1 = base + 4 + g, e2 = base + 8 + g, e3 = base + 12 + g;
        unsigned int p0 = perm[e0 <= last ? e0 : last];
        unsigned int p1 = perm[e1 <= last ? e1 : last];
        unsigned int p2 = perm[e2 <= last ? e2 : last];
        unsigned int p3 = perm[e3 <= last ? e3 : last];
        uint2 a0 = *(const uint2*)&h[(size_t)(p0 & SRC_MASK) * 64 + lc * 4];
        uint2 a1 = *(const uint2*)&h[(size_t)(p1 & SRC_MASK) * 64 + lc * 4];
        uint2 a2 = *(const uint2*)&h[(size_t)(p2 & SRC_MASK) * 64 + lc * 4];
        uint2 a3 = *(const uint2*)&h[(size_t)(p3 & SRC_MASK) * 64 + lc * 4];
        float w0 = e0 <= last ? pw_w(p0) : 0.f;
        float w1 = e1 <= last ? pw_w(p1) : 0.f;
        float w2 = e2 <= last ? pw_w(p2) : 0.f;
        float w3 = e3 <= last ? pw_w(p3) : 0.f;
        acc4(acc, a0, w0);
        acc4(acc, a1, w1);
        acc4(acc, a2, w2);
        acc4(acc, a3, w3);
    }
#pragma unroll
    for (int i = 0; i < 4; i++) {
        acc[i] += __shfl_xor(acc[i], 16);
        acc[i] += __shfl_xor(acc[i], 32);
    }

    bool vf = l < 10;
    float m = vf ? fmaxf(fmaxf(acc[0], acc[1]), fmaxf(acc[2], acc[3]))
                 : -__builtin_inff();
#pragma unroll
    for (int off = 1; off < 16; off <<= 1) m = fmaxf(m, __shfl_xor(m, off));
    float s = vf ? (expf(acc[0] - m) + expf(acc[1] - m) +
                    expf(acc[2] - m) + expf(acc[3] - m))
                 : 0.f;
#pragma unroll
    for (int off = 1; off < 16; off <<= 1) s += __shfl_xor(s, off);
    float ls = m + logf(s);
    if (g == 0 && vf) {
        float4 o = make_float4(acc[0] - ls, acc[1] - ls, acc[2] - ls, acc[3] - ls);
        *(float4*)&out[(size_t)node * 40 + l * 4] = o;
    }
}

extern "C" void kernel_launch(void* const* d_in, const int* in_sizes, int n_in,
                              void* d_out, int out_size, void* d_ws, size_t ws_size,
                              hipStream_t stream) {
    const float* x  = (const float*)d_in[0];
    const int*   src = (const int*)d_in[1];
    const int*   tgt = (const int*)d_in[2];
    const float* ew  = (const float*)d_in[3];
    const float* W0 = (const float*)d_in[4];
    const float* b0 = (const float*)d_in[5];
    const float* W1 = (const float*)d_in[6];
    const float* b1 = (const float*)d_in[7];
    const float* W2 = (const float*)d_in[8];
    const float* b2 = (const float*)d_in[9];
    const float* W3 = (const float*)d_in[10];
    const float* b3 = (const float*)d_in[11];

    const int N = in_sizes[0] / 256;
    const int E = in_sizes[1];
    const int NSC = (N + SC_NODES - 1) >> SC_SHIFT;

    char* ws = (char*)d_ws;
    size_t off = 0;
    auto alloc = [&](size_t bytes) -> void* {
        void* p = ws + off;
        off = (off + bytes + 255) & ~(size_t)255;
        return p;
    };
    unsigned short* XCb = (unsigned short*)alloc((size_t)N * 128 * 2);
    size_t hbytes = (size_t)N * 128 * 2;
    size_t sbytes = (size_t)E * 5 + 256;
    char* hbuf = (char*)alloc(hbytes > sbytes ? hbytes : sbytes);
    unsigned short* Hb = (unsigned short*)hbuf;
    unsigned int* st_pw = (unsigned int*)hbuf;
    unsigned char* st_t8 = (unsigned char*)(hbuf + (size_t)E * 4);
    char* buf1 = (char*)alloc((size_t)N * 128 * 2);
    unsigned short* XAb  = (unsigned short*)buf1;
    unsigned short* H40b = (unsigned short*)buf1;
    unsigned short* XBb  = (unsigned short*)alloc((size_t)N * 128 * 2);
    int*   rowptr    = (int*)alloc((size_t)(N + 1) * 4);
    int*   chunkTot  = (int*)alloc(512 * 4);
    int*   chunkStart= (int*)alloc(520 * 4);
    int*   chunkCur  = (int*)alloc(512 * 32 * 4);
    unsigned int* perm = (unsigned int*)alloc((size_t)E * 4);
    unsigned short* Wt0 = (unsigned short*)alloc(256 * 128 * 2);
    unsigned short* Wt1 = (unsigned short*)alloc(128 * 128 * 2);
    unsigned short* Wt2 = (unsigned short*)alloc(128 * 128 * 2);
    unsigned short* Wt3 = (unsigned short*)alloc(48 * 128 * 2);
    (void)ws_size;

    float* logits = (float*)d_out;

    k_wtrans_all<<<(71680 + 255) / 256, 256, 0, stream>>>(W0, W1, W2, W3,
                                                          Wt0, Wt1, Wt2, Wt3,
                                                          chunkTot);
    k_count<<<(E + 4095) / 4096, 256, 0, stream>>>(tgt, chunkTot, E, NSC);
    k_scanB<<<1, 512, 0, stream>>>(chunkTot, chunkStart, chunkCur, E, NSC);
    k_bucket<<<(E + 8191) / 8192, 512, 0, stream>>>(src, tgt, ew, chunkCur,
                                                    st_pw, st_t8, E);
    k_fill2<<<NSC, 256, 0, stream>>>(st_pw, st_t8, chunkStart, rowptr, perm,
                                     N, E, NSC);

    const int gGemm = (N + 63) / 64;
    const int gWave = (N + 3) / 4;

    // L0 (reads fp32 x directly)
    k_gemm_mfma<256, 1><<<gGemm, 256, 0, stream>>>(x, Wt0, b0, Hb, N);
    k_agg128<<<gWave, 256, 0, stream>>>(Hb, rowptr, perm, nullptr, XAb, N);
    // L1
    k_gemm_mfma<128, 0><<<gGemm, 256, 0, stream>>>(XAb, Wt1, b1, Hb, N);
    k_agg128<<<gWave, 256, 0, stream>>>(Hb, rowptr, perm, nullptr, XBb, N);
    // L2 (+residual XAb) -> XCb
    k_gemm_mfma<128, 0><<<gGemm, 256, 0, stream>>>(XBb, Wt2, b2, Hb, N);
    k_agg128<<<gWave, 256, 0, stream>>>(Hb, rowptr, perm, XAb, XCb, N);
    // L3
    k_gemm40_mfma<<<gGemm, 256, 0, stream>>>(XCb, Wt3, b3, H40b, N);
    k_agg40_lsm<<<gWave, 256, 0, stream>>>(H40b, rowptr, perm, logits, N);
}